// Round 9
// baseline (174.061 us; speedup 1.0000x reference)
//
#include <hip/hip_runtime.h>
#include <hip/hip_bf16.h>

typedef __attribute__((ext_vector_type(8))) short short8;
typedef __attribute__((ext_vector_type(4))) float f32x4;

#define BM 128
#define BN 256
#define BK 32
#define LDST 36   // bf16 elems per LDS row (32+4): 72 B rows -> 16 distinct bank starts
#define NKT 16    // 512 / BK

static __device__ __forceinline__ unsigned short f2bf(float f) {
    union { __hip_bfloat16 h; unsigned short u; } cv;
    cv.h = __float2bfloat16(f);
    return cv.u;
}

// Build Wbig[m=o*8+k][kk=f*8+j] = sum_i C[i,j,k] * W[i,o,f], cast to bf16.
__global__ __launch_bounds__(256) void build_wbig(const float* __restrict__ W,
                                                  unsigned short* __restrict__ Wbig) {
    __shared__ float C[8][8][8];
    const int t = threadIdx.x;
    for (int i = t; i < 512; i += 256) ((float*)C)[i] = 0.0f;
    __syncthreads();
    if (t == 0) {
        C[0][0][0] = 1.0f;
        for (int i = 1; i < 8; ++i) { C[0][i][i] = 1.0f; C[i][0][i] = 1.0f; C[i][i][0] = -1.0f; }
        const int tr[7][3] = {{1,2,3},{1,4,5},{1,7,6},{2,4,6},{2,5,7},{3,4,7},{3,6,5}};
        for (int q = 0; q < 7; ++q) {
            const int a = tr[q][0], b = tr[q][1], c = tr[q][2];
            const int p[3][3] = {{a,b,c},{b,c,a},{c,a,b}};
            for (int u = 0; u < 3; ++u) {
                C[p[u][0]][p[u][1]][p[u][2]] = 1.0f;
                C[p[u][1]][p[u][0]][p[u][2]] = -1.0f;
            }
        }
    }
    __syncthreads();
    const int e = blockIdx.x * 256 + t;     // 0..262143
    const int m = e >> 9, kk = e & 511;
    const int o = m >> 3, k = m & 7, f = kk >> 3, j = kk & 7;
    float s = 0.0f;
#pragma unroll
    for (int i = 0; i < 8; ++i) s += C[i][j][k] * W[i * 4096 + o * 64 + f];
    Wbig[e] = f2bf(s);
}

// Out[65536][512] = X(fp32->bf16) * Wbig^T + bias.
// 128x256 tile, 8 waves (64x64 wave-tile, acc=64 VGPR), BK=32, LDS 54 KB ->
// 2 blocks/CU (16 waves/CU). No-drain schedule, prefetch distance 2:
//   iter t: ISSUE(t+2)->set[t&1] | MFMA on buf[t&1] (LDS-only) |
//           WRITE(t+1) set[(t+1)&1]->buf[(t+1)&1] (counted vmcnt, 4 in flight) |
//           lgkmcnt(0) + raw s_barrier.   vmcnt never drained.
__global__ __launch_bounds__(512, 4) void oct_gemm(const float* __restrict__ X,
                                                   const unsigned short* __restrict__ Wbig,
                                                   const float* __restrict__ Bias,
                                                   float* __restrict__ Out) {
    __shared__ unsigned short As[2][BM * LDST];   // 2 x 9 KB
    __shared__ unsigned short Bs[2][BN * LDST];   // 2 x 18 KB

    // XCD swizzle: both col-tiles of a row-tile on the same XCD (1024 % 8 == 0).
    const int bid   = blockIdx.x;        // 0..1023
    const int xcd   = bid & 7;
    const int ix    = bid >> 3;          // 0..127
    const int mtile = xcd * 64 + (ix >> 1);
    const int ntile = ix & 1;
    const int rowBase = mtile * BM;
    const int colBase = ntile * BN;

    const int t    = threadIdx.x;        // 0..511
    const int lane = t & 63;
    const int wave = t >> 6;             // 0..7
    const int wr   = wave >> 2;          // 0..1  (64-row half)
    const int wc   = wave & 3;           // 0..3  (64-col quarter)
    const int l15  = lane & 15;
    const int l4   = lane >> 4;          // 0..3

    // Staging coords. A: 4 thr/row x 8 fp32 (32 B). B: 2 thr/row x 16 bf16 (32 B).
    const int arow = t >> 2, ac = (t & 3) * 8;
    const int brow = t >> 1, bc = (t & 1) * 16;

    const float*          Xp = X    + (size_t)(rowBase + arow) * 512 + ac;
    const unsigned short* Bp = Wbig + (size_t)(colBase + brow) * 512 + bc;

    f32x4  va[2][2];   // 2 sets x 8 fp32  (16 VGPR)
    short8 vb[2][2];   // 2 sets x 16 bf16 (16 VGPR)

#define ISSUE(SET, KT) do { \
    va[SET][0] = *reinterpret_cast<const f32x4*>(Xp + (KT)); \
    va[SET][1] = *reinterpret_cast<const f32x4*>(Xp + (KT) + 4); \
    vb[SET][0] = *reinterpret_cast<const short8*>(Bp + (KT)); \
    vb[SET][1] = *reinterpret_cast<const short8*>(Bp + (KT) + 8); \
    } while (0)

#define WRITE(SET, BUF) do { \
    short8 p; \
    p[0]=(short)f2bf(va[SET][0][0]); p[1]=(short)f2bf(va[SET][0][1]); \
    p[2]=(short)f2bf(va[SET][0][2]); p[3]=(short)f2bf(va[SET][0][3]); \
    p[4]=(short)f2bf(va[SET][1][0]); p[5]=(short)f2bf(va[SET][1][1]); \
    p[6]=(short)f2bf(va[SET][1][2]); p[7]=(short)f2bf(va[SET][1][3]); \
    *reinterpret_cast<short8*>(&As[BUF][arow * LDST + ac]) = p; \
    *reinterpret_cast<short8*>(&Bs[BUF][brow * LDST + bc]) = vb[SET][0]; \
    *reinterpret_cast<short8*>(&Bs[BUF][brow * LDST + bc + 8]) = vb[SET][1]; \
    } while (0)

    // Bias folded into accumulator init (D col = lane&15 for all 4 regs).
    f32x4 acc[4][4];
#pragma unroll
    for (int ni = 0; ni < 4; ++ni) {
        const float bv = Bias[colBase + wc * 64 + ni * 16 + l15];
#pragma unroll
        for (int mi = 0; mi < 4; ++mi) acc[mi][ni] = (f32x4){bv, bv, bv, bv};
    }

    // Prologue: tiles 0,1 in flight; stage tile 0 (counted vmcnt keeps set1 in flight).
    ISSUE(0, 0);
    ISSUE(1, BK);
    WRITE(0, 0);
    asm volatile("s_waitcnt lgkmcnt(0)" ::: "memory");
    __builtin_amdgcn_s_barrier();

#pragma unroll
    for (int kt = 0; kt < NKT; ++kt) {
        // issue tile kt+2 into set[kt&1] (its tile kt was staged last iter)
        if (kt + 2 < NKT) ISSUE(kt & 1, (kt + 2) * BK);
        __builtin_amdgcn_sched_barrier(0);

        // MFMA phase: LDS-only operands (compiler emits counted lgkmcnt)
        {
            const int kb = l4 * 8;
            short8 b[4];
#pragma unroll
            for (int ni = 0; ni < 4; ++ni)
                b[ni] = *reinterpret_cast<const short8*>(
                    &Bs[kt & 1][(wc * 64 + ni * 16 + l15) * LDST + kb]);
            __builtin_amdgcn_s_setprio(1);
#pragma unroll
            for (int mi = 0; mi < 4; ++mi) {
                const short8 a = *reinterpret_cast<const short8*>(
                    &As[kt & 1][(wr * 64 + mi * 16 + l15) * LDST + kb]);
#pragma unroll
                for (int ni = 0; ni < 4; ++ni)
                    acc[mi][ni] = __builtin_amdgcn_mfma_f32_16x16x32_bf16(
                        a, b[ni], acc[mi][ni], 0, 0, 0);
            }
            __builtin_amdgcn_s_setprio(0);
        }
        __builtin_amdgcn_sched_barrier(0);

        // stage tile kt+1 (vmcnt auto-counted: waits only set[(kt+1)&1]'s 4 loads)
        if (kt + 1 < NKT) WRITE((kt + 1) & 1, (kt + 1) & 1);

        asm volatile("s_waitcnt lgkmcnt(0)" ::: "memory");
        __builtin_amdgcn_s_barrier();
    }

    // Epilogue: plain fp32 stores (verified clean 131 MB write pattern).
#pragma unroll
    for (int mi = 0; mi < 4; ++mi) {
        const int row0 = rowBase + wr * 64 + mi * 16 + l4 * 4;
#pragma unroll
        for (int ni = 0; ni < 4; ++ni) {
            const int col = colBase + wc * 64 + ni * 16 + l15;
#pragma unroll
            for (int r = 0; r < 4; ++r)
                Out[(size_t)(row0 + r) * 512 + col] = acc[mi][ni][r];
        }
    }
#undef ISSUE
#undef WRITE
}

extern "C" void kernel_launch(void* const* d_in, const int* in_sizes, int n_in,
                              void* d_out, int out_size, void* d_ws, size_t ws_size,
                              hipStream_t stream) {
    const float* x = (const float*)d_in[0];   // [65536][512]
    const float* W = (const float*)d_in[1];   // [8][64][64]
    const float* b = (const float*)d_in[2];   // [512]
    float* out = (float*)d_out;               // [65536][512]
    unsigned short* Wbig = (unsigned short*)d_ws;  // 512*512 bf16 = 512 KB

    build_wbig<<<1024, 256, 0, stream>>>(W, Wbig);
    oct_gemm<<<1024, 512, 0, stream>>>(x, Wbig, b, out);
}

// Round 10
// 97.892 us; speedup vs baseline: 1.7781x; 1.7781x over previous
//
#include <hip/hip_runtime.h>
#include <hip/hip_bf16.h>

typedef __attribute__((ext_vector_type(8))) short short8;
typedef __attribute__((ext_vector_type(4))) float f32x4;

#define BM 128
#define BN 256
#define BK 32
#define LDST 36   // bf16 elems per LDS A row (32+4 pad): 72 B rows -> ~2-way (free)
#define NKT 16    // 512 / BK

static __device__ __forceinline__ unsigned short f2bf(float f) {
    union { __hip_bfloat16 h; unsigned short u; } cv;
    cv.h = __float2bfloat16(f);
    return cv.u;
}

// Build Wbig[m=o*8+k][kk=f*8+j] = sum_i C[i,j,k] * W[i,o,f], cast to bf16.
__global__ __launch_bounds__(256) void build_wbig(const float* __restrict__ W,
                                                  unsigned short* __restrict__ Wbig) {
    __shared__ float C[8][8][8];
    const int t = threadIdx.x;
    for (int i = t; i < 512; i += 256) ((float*)C)[i] = 0.0f;
    __syncthreads();
    if (t == 0) {
        C[0][0][0] = 1.0f;
        for (int i = 1; i < 8; ++i) { C[0][i][i] = 1.0f; C[i][0][i] = 1.0f; C[i][i][0] = -1.0f; }
        const int tr[7][3] = {{1,2,3},{1,4,5},{1,7,6},{2,4,6},{2,5,7},{3,4,7},{3,6,5}};
        for (int q = 0; q < 7; ++q) {
            const int a = tr[q][0], b = tr[q][1], c = tr[q][2];
            const int p[3][3] = {{a,b,c},{b,c,a},{c,a,b}};
            for (int u = 0; u < 3; ++u) {
                C[p[u][0]][p[u][1]][p[u][2]] = 1.0f;
                C[p[u][1]][p[u][0]][p[u][2]] = -1.0f;
            }
        }
    }
    __syncthreads();
    const int e = blockIdx.x * 256 + t;     // 0..262143
    const int m = e >> 9, kk = e & 511;
    const int o = m >> 3, k = m & 7, f = kk >> 3, j = kk & 7;
    float s = 0.0f;
#pragma unroll
    for (int i = 0; i < 8; ++i) s += C[i][j][k] * W[i * 4096 + o * 64 + f];
    Wbig[e] = f2bf(s);
}

// Out[65536][512] = X(fp32->bf16) * Wbig^T + bias.
// 128x256 tile, 8 waves (64x64 wave-tile). Register budget designed to
// 128 total/wave (4 waves/SIMD, 2 blocks/CU): acc 64 AGPR + ~50 VGPR.
// A: 18 KB LDS double-buffer, depth-1 reg staging (8 VGPR).
// B: NO LDS -- frag regs b[4] loaded direct from L2-resident Wbig, re-issued
// into the same regs right after last use (single 16-VGPR lifetime).
// No-drain schedule: counted vmcnt at ds_write; lgkmcnt(0)+raw s_barrier only.
__global__ __launch_bounds__(512, 4) void oct_gemm(const float* __restrict__ X,
                                                   const unsigned short* __restrict__ Wbig,
                                                   const float* __restrict__ Bias,
                                                   float* __restrict__ Out) {
    __shared__ unsigned short As[2][BM * LDST];   // 2 x 9 KB

    // XCD pairing: both col-tiles of a row-tile on the same XCD (1024 % 8 == 0).
    const int bid   = blockIdx.x;        // 0..1023
    const int xcd   = bid & 7;
    const int ix    = bid >> 3;          // 0..127
    const int mtile = xcd * 64 + (ix >> 1);
    const int ntile = ix & 1;
    const int rowBase = mtile * BM;
    const int colBase = ntile * BN;

    const int t    = threadIdx.x;        // 0..511
    const int lane = t & 63;
    const int wave = t >> 6;             // 0..7
    const int wr   = wave >> 2;          // 0..1  (64-row half)
    const int wc   = wave & 3;           // 0..3  (64-col quarter)
    const int l15  = lane & 15;
    const int l4   = lane >> 4;          // 0..3

    // A staging: 4 thr/row x 8 fp32 (32 B each)
    const int arow = t >> 2, ac = (t & 3) * 8;
    const float* Xp = X + (size_t)(rowBase + arow) * 512 + ac;

    // B frag base: row = colBase + wc*64 + ni*16 + l15, k-off = l4*8
    const unsigned short* Bb = Wbig + (size_t)(colBase + wc * 64 + l15) * 512 + l4 * 8;

    f32x4  va[2];   // in-flight A (8 VGPR)
    short8 b[4];    // B frags, single lifetime (16 VGPR)

#define ISSUE_A(KT) do { \
    va[0] = *reinterpret_cast<const f32x4*>(Xp + (KT)); \
    va[1] = *reinterpret_cast<const f32x4*>(Xp + (KT) + 4); \
    } while (0)

#define ISSUE_B(KT) do { _Pragma("unroll") \
    for (int ni = 0; ni < 4; ++ni) \
        b[ni] = *reinterpret_cast<const short8*>(Bb + (size_t)ni * (16 * 512) + (KT)); \
    } while (0)

#define WRITE_A(BUF) do { \
    short8 p; \
    p[0]=(short)f2bf(va[0][0]); p[1]=(short)f2bf(va[0][1]); \
    p[2]=(short)f2bf(va[0][2]); p[3]=(short)f2bf(va[0][3]); \
    p[4]=(short)f2bf(va[1][0]); p[5]=(short)f2bf(va[1][1]); \
    p[6]=(short)f2bf(va[1][2]); p[7]=(short)f2bf(va[1][3]); \
    *reinterpret_cast<short8*>(&As[BUF][arow * LDST + ac]) = p; \
    } while (0)

    // Bias folded into accumulator init (D col = lane&15 for all 4 regs).
    f32x4 acc[4][4];
#pragma unroll
    for (int ni = 0; ni < 4; ++ni) {
        const float bv = Bias[colBase + wc * 64 + ni * 16 + l15];
#pragma unroll
        for (int mi = 0; mi < 4; ++mi) acc[mi][ni] = (f32x4){bv, bv, bv, bv};
    }

    // Prologue: A(0) staged (counted vmcnt leaves B(0) in flight), b(0) loaded.
    ISSUE_A(0);
    ISSUE_B(0);
    WRITE_A(0);
    asm volatile("s_waitcnt lgkmcnt(0)" ::: "memory");
    __builtin_amdgcn_s_barrier();

#pragma unroll
    for (int kt = 0; kt < NKT; ++kt) {
        // issue next A tile (longest latency: HBM/L3)
        if (kt + 1 < NKT) ISSUE_A((kt + 1) * BK);
        __builtin_amdgcn_sched_barrier(0);

        // MFMA phase: LDS A frags + register B (16 MFMA/wave)
        {
            const int kb = l4 * 8;
            __builtin_amdgcn_s_setprio(1);
#pragma unroll
            for (int mi = 0; mi < 4; ++mi) {
                const short8 a = *reinterpret_cast<const short8*>(
                    &As[kt & 1][(wr * 64 + mi * 16 + l15) * LDST + kb]);
#pragma unroll
                for (int ni = 0; ni < 4; ++ni)
                    acc[mi][ni] = __builtin_amdgcn_mfma_f32_16x16x32_bf16(
                        a, b[ni], acc[mi][ni], 0, 0, 0);
            }
            __builtin_amdgcn_s_setprio(0);
        }
        __builtin_amdgcn_sched_barrier(0);

        // b's last use is behind us: re-issue B for next iter into the SAME regs
        if (kt + 1 < NKT) ISSUE_B((kt + 1) * BK);

        // stage A(t+1): counted vmcnt (waits A loads, leaves B in flight)
        if (kt + 1 < NKT) WRITE_A((kt + 1) & 1);

        asm volatile("s_waitcnt lgkmcnt(0)" ::: "memory");
        __builtin_amdgcn_s_barrier();
    }

    // Epilogue: plain fp32 stores (verified clean 131 MB write pattern).
#pragma unroll
    for (int mi = 0; mi < 4; ++mi) {
        const int row0 = rowBase + wr * 64 + mi * 16 + l4 * 4;
#pragma unroll
        for (int ni = 0; ni < 4; ++ni) {
            const int col = colBase + wc * 64 + ni * 16 + l15;
#pragma unroll
            for (int r = 0; r < 4; ++r)
                Out[(size_t)(row0 + r) * 512 + col] = acc[mi][ni][r];
        }
    }
#undef ISSUE_A
#undef ISSUE_B
#undef WRITE_A
}

extern "C" void kernel_launch(void* const* d_in, const int* in_sizes, int n_in,
                              void* d_out, int out_size, void* d_ws, size_t ws_size,
                              hipStream_t stream) {
    const float* x = (const float*)d_in[0];   // [65536][512]
    const float* W = (const float*)d_in[1];   // [8][64][64]
    const float* b = (const float*)d_in[2];   // [512]
    float* out = (float*)d_out;               // [65536][512]
    unsigned short* Wbig = (unsigned short*)d_ws;  // 512*512 bf16 = 512 KB

    build_wbig<<<1024, 256, 0, stream>>>(W, Wbig);
    oct_gemm<<<1024, 512, 0, stream>>>(x, Wbig, b, out);
}